// Round 1
// baseline (976.084 us; speedup 1.0000x reference)
//
#include <hip/hip_runtime.h>
#include <hip/hip_bf16.h>

#define DEV __device__ __forceinline__

typedef unsigned short u16;
typedef unsigned int u32;
typedef __attribute__((ext_vector_type(8))) short s16x8;   // 8 bf16 in 4 VGPRs
typedef __attribute__((ext_vector_type(4))) float f32x4;

constexpr int B_  = 2, S_ = 2048, D_ = 4096, NH = 32, NKV = 8, HD = 128;
constexpr int M_  = B_ * S_;        // 4096 rows of "tokens"
constexpr int FQ  = 6144;           // Q(4096) + K(1024) + V(1024)
constexpr float SCALE = 0.08838834764831845f;   // 1/sqrt(128)
constexpr float LOG2E = 1.4426950408889634f;
constexpr float LOG2_THETA = 18.931568569324174f; // log2(500000)

DEV u16 f2bf(float f) {
  u32 u = __builtin_bit_cast(u32, f);
  u32 r = u + 0x7fffu + ((u >> 16) & 1u);
  return (u16)(r >> 16);
}
DEV float bf2f(u16 h) { u32 u = ((u32)h) << 16; return __builtin_bit_cast(float, u); }

DEV void gload_lds16(const void* g, void* l) {
  __builtin_amdgcn_global_load_lds((const __attribute__((address_space(1))) u32*)g,
                                   (__attribute__((address_space(3))) u32*)l, 16, 0, 0);
}

// ---------------------------------------------------------------------------
// elementwise f32 -> bf16 cast (vectorized)
// ---------------------------------------------------------------------------
struct alignas(8) U16x4 { u16 x, y, z, w; };

__global__ __launch_bounds__(256) void cast_f32_bf16(const float* __restrict__ src,
                                                     u16* __restrict__ dst, int n4) {
  int i = blockIdx.x * 256 + threadIdx.x;
  if (i < n4) {
    float4 v = ((const float4*)src)[i];
    U16x4 o; o.x = f2bf(v.x); o.y = f2bf(v.y); o.z = f2bf(v.z); o.w = f2bf(v.w);
    ((U16x4*)dst)[i] = o;
  }
}

// ---------------------------------------------------------------------------
// transpose + cast: src f32 [R][C] -> dst bf16 [C][R]
// ---------------------------------------------------------------------------
__global__ __launch_bounds__(256) void transpose_cast_w(const float* __restrict__ src,
                                                        u16* __restrict__ dst, int R, int C) {
  __shared__ float tile[32][33];
  const int tx = threadIdx.x & 31, ty = threadIdx.x >> 5;
  const int c0 = blockIdx.x * 32, r0 = blockIdx.y * 32;
#pragma unroll
  for (int i = 0; i < 4; ++i)
    tile[ty + i * 8][tx] = src[(size_t)(r0 + ty + i * 8) * C + c0 + tx];
  __syncthreads();
#pragma unroll
  for (int i = 0; i < 4; ++i)
    dst[(size_t)(c0 + ty + i * 8) * R + r0 + tx] = f2bf(tile[tx][ty + i * 8]);
}

// bf16 [S][HD] -> [HD][S] per head (16 heads in z)
__global__ __launch_bounds__(256) void transpose_v16(const u16* __restrict__ Vb,
                                                     u16* __restrict__ Vt) {
  __shared__ u16 tile[32][33];
  const int tx = threadIdx.x & 31, ty = threadIdx.x >> 5;
  const int d0 = blockIdx.x * 32, s0 = blockIdx.y * 32;
  const size_t head = blockIdx.z;
  const u16* sp = Vb + head * (size_t)S_ * HD;
  u16* dp = Vt + head * (size_t)HD * S_;
#pragma unroll
  for (int i = 0; i < 4; ++i)
    tile[ty + i * 8][tx] = sp[(size_t)(s0 + ty + i * 8) * HD + d0 + tx];
  __syncthreads();
#pragma unroll
  for (int i = 0; i < 4; ++i)
    dp[(size_t)(d0 + ty + i * 8) * S_ + s0 + tx] = tile[tx][ty + i * 8];
}

// ---------------------------------------------------------------------------
// GEMM: C[M][N] = A[M][K](bf16,row-major) * Bt[N][K](bf16,row-major, i.e. B^T)
// 128x128 tile, BK=32, 4 waves (2x2), double-buffered LDS via global_load_lds.
// LDS tiles are [128 rows][32 cols] bf16 = 64B rows of 4 16B slots; slot is
// XOR-swizzled with ((row>>1)&3) — applied on the GLOBAL source address
// (gload_lds writes linearly) and again on the ds_read side.
// ---------------------------------------------------------------------------
DEV void stage_tile(const u16* __restrict__ gtile, int ldg, u16* lds, int wid, int lane) {
#pragma unroll
  for (int i = 0; i < 2; ++i) {
    int c = (i * 4 + wid) * 64 + lane;       // chunk id 0..511
    int row = c >> 2, slot = c & 3;
    int ss = slot ^ ((row >> 1) & 3);
    gload_lds16(gtile + (size_t)row * ldg + ss * 8, lds + (size_t)(i * 4 + wid) * 512);
  }
}

DEV s16x8 frag64(const u16* lds, int row, int hi) {
  int ss = hi ^ ((row >> 1) & 3);
  return *(const s16x8*)(lds + row * 32 + ss * 8);
}

template <bool OUT_BF16>
__global__ __launch_bounds__(256) void gemm_bt(const u16* __restrict__ A,
                                               const u16* __restrict__ Bt,
                                               void* __restrict__ Cv,
                                               int Mm, int Nn, int Kk) {
  __shared__ u16 As[2][128 * 32];
  __shared__ u16 Bs[2][128 * 32];
  const int lane = threadIdx.x & 63, wid = threadIdx.x >> 6;
  const int lo = lane & 15, hi = lane >> 4;
  const int m0 = blockIdx.y * 128, n0 = blockIdx.x * 128;
  const u16* Ag = A + (size_t)m0 * Kk;
  const u16* Bg = Bt + (size_t)n0 * Kk;
  f32x4 acc[4][4] = {};
  const int nK = Kk >> 5;
  stage_tile(Ag, Kk, As[0], wid, lane);
  stage_tile(Bg, Kk, Bs[0], wid, lane);
  __syncthreads();
  const int wm = (wid >> 1) * 64, wn = (wid & 1) * 64;
  for (int kt = 0; kt < nK; ++kt) {
    const int cur = kt & 1;
    if (kt + 1 < nK) {
      stage_tile(Ag + (kt + 1) * 32, Kk, As[cur ^ 1], wid, lane);
      stage_tile(Bg + (kt + 1) * 32, Kk, Bs[cur ^ 1], wid, lane);
    }
    s16x8 af[4], bf[4];
#pragma unroll
    for (int t = 0; t < 4; ++t) af[t] = frag64(As[cur], wm + t * 16 + lo, hi);
#pragma unroll
    for (int t = 0; t < 4; ++t) bf[t] = frag64(Bs[cur], wn + t * 16 + lo, hi);
#pragma unroll
    for (int i = 0; i < 4; ++i)
#pragma unroll
      for (int j = 0; j < 4; ++j)
        acc[i][j] = __builtin_amdgcn_mfma_f32_16x16x32_bf16(af[i], bf[j], acc[i][j], 0, 0, 0);
    __syncthreads();
  }
#pragma unroll
  for (int i = 0; i < 4; ++i)
#pragma unroll
    for (int j = 0; j < 4; ++j)
#pragma unroll
      for (int r = 0; r < 4; ++r) {
        int row = m0 + wm + i * 16 + hi * 4 + r;
        int col = n0 + wn + j * 16 + lo;
        float v = acc[i][j][r];
        if (OUT_BF16) ((u16*)Cv)[(size_t)row * Nn + col] = f2bf(v);
        else          ((float*)Cv)[(size_t)row * Nn + col] = v;
      }
}

// ---------------------------------------------------------------------------
// RoPE + head split: QKV bf16 [M][6144] -> Qb [b][h][s][hd], Kb [b][kv][s][hd]
// (both rotated), Vb [b][kv][s][hd] (copy).
// ---------------------------------------------------------------------------
__global__ __launch_bounds__(256) void rope_split(const u16* __restrict__ QKV,
                                                  const int* __restrict__ pos,
                                                  u16* __restrict__ Qb, u16* __restrict__ Kb,
                                                  u16* __restrict__ Vb) {
  const int row = blockIdx.x;              // b*S + s
  const int b = row >> 11, s = row & 2047;
  const float t = (float)pos[row];
  const u16* src = QKV + (size_t)row * FQ;
  for (int idx = threadIdx.x; idx < 2560; idx += 256) {
    int j; const u16* sp; u16* dp;
    if (idx < 2048) {
      int hh = idx >> 6; j = idx & 63;
      sp = src + hh * 128 + 2 * j;
      dp = Qb + ((size_t)(b * NH + hh) * S_ + s) * HD + 2 * j;
    } else {
      int p2 = idx - 2048; int kvh = p2 >> 6; j = p2 & 63;
      sp = src + 4096 + kvh * 128 + 2 * j;
      dp = Kb + ((size_t)(b * NKV + kvh) * S_ + s) * HD + 2 * j;
    }
    float a = bf2f(sp[0]), bb = bf2f(sp[1]);
    float ang = t * exp2f(-(float)j * (LOG2_THETA / 64.0f));
    float sn, cs; sincosf(ang, &sn, &cs);
    dp[0] = f2bf(a * cs - bb * sn);
    dp[1] = f2bf(a * sn + bb * cs);
  }
  for (int idx = threadIdx.x; idx < 1024; idx += 256) {
    int kvh = idx >> 7, hd = idx & 127;
    Vb[((size_t)(b * NKV + kvh) * S_ + s) * HD + hd] = src[5120 + idx];
  }
}

// ---------------------------------------------------------------------------
// Flash attention. Block = 256 threads (4 waves = the 4 GQA heads of one kv
// group) x one 16-row Q tile. KV tiles of 32, staged in LDS (K row-major
// swizzled, V^T 64B-rows swizzled). Wave-parallel online softmax.
// ---------------------------------------------------------------------------
__global__ __launch_bounds__(256) void attn_fwd(const u16* __restrict__ Qb,
                                                const u16* __restrict__ Kb,
                                                const u16* __restrict__ Vt,
                                                const float* __restrict__ mask,
                                                u16* __restrict__ Ob) {
  __shared__ u16 Ks[32 * 128];   // K tile: 32 rows x 128 d (256B rows, 16 slots, ^(row&7))
  __shared__ u16 Vs[128 * 32];   // V^T tile: 128 rows x 32 s (64B rows, 4 slots, ^((row>>1)&3))
  __shared__ u16 Ps[4][16 * 32]; // per-wave P tile (64B rows, ^((row>>1)&3))
  const int lane = threadIdx.x & 63, wid = threadIdx.x >> 6;
  const int lo = lane & 15, hi = lane >> 4;
  const int qt = blockIdx.x, bkv = blockIdx.y;
  const int b = bkv >> 3, kv = bkv & 7;
  const int h = kv * 4 + wid;
  const int q0 = qt * 16;
  const u16* Qg = Qb + ((size_t)(b * NH + h) * S_ + q0) * HD;
  const u16* Kg = Kb + (size_t)(b * NKV + kv) * S_ * HD;
  const u16* Vg = Vt + (size_t)(b * NKV + kv) * HD * S_;
  s16x8 qf[4];
#pragma unroll
  for (int c = 0; c < 4; ++c)
    qf[c] = *(const s16x8*)(Qg + (size_t)lo * HD + c * 32 + hi * 8);
  float mreg[4], lreg[4];
  f32x4 acc[8] = {};
#pragma unroll
  for (int r = 0; r < 4; ++r) { mreg[r] = -1e30f; lreg[r] = 0.f; }
  const int nt = (q0 + 47) >> 5;   // causal: only tiles with k0 <= q0+15
  for (int t = 0; t < nt; ++t) {
    const int k0 = t * 32;
#pragma unroll
    for (int i = 0; i < 2; ++i) {  // stage K: 512 chunks of 16B
      int c = (i * 4 + wid) * 64 + lane;
      int row = c >> 4, sl = c & 15, ss = sl ^ (row & 7);
      gload_lds16(Kg + (size_t)(k0 + row) * HD + ss * 8, Ks + (size_t)(i * 4 + wid) * 512);
    }
#pragma unroll
    for (int i = 0; i < 2; ++i) {  // stage V^T: 512 chunks of 16B
      int c = (i * 4 + wid) * 64 + lane;
      int row = c >> 2, sl = c & 3, ss = sl ^ ((row >> 1) & 3);
      gload_lds16(Vg + (size_t)row * S_ + k0 + ss * 8, Vs + (size_t)(i * 4 + wid) * 512);
    }
    __syncthreads();
    // QK^T: S[q][k] for two 16-key column blocks
    f32x4 s0 = {}, s1 = {};
#pragma unroll
    for (int c = 0; c < 4; ++c) {
      int r0 = lo, r1 = 16 + lo;
      int sl0 = (c * 4 + hi) ^ (r0 & 7);
      int sl1 = (c * 4 + hi) ^ (r1 & 7);
      s16x8 kf0 = *(const s16x8*)(Ks + r0 * 128 + sl0 * 8);
      s16x8 kf1 = *(const s16x8*)(Ks + r1 * 128 + sl1 * 8);
      s0 = __builtin_amdgcn_mfma_f32_16x16x32_bf16(qf[c], kf0, s0, 0, 0, 0);
      s1 = __builtin_amdgcn_mfma_f32_16x16x32_bf16(qf[c], kf1, s1, 0, 0, 0);
    }
    const float mv0 = mask[b * S_ + k0 + lo];
    const float mv1 = mask[b * S_ + k0 + 16 + lo];
    u16* Pw = Ps[wid];
#pragma unroll
    for (int r = 0; r < 4; ++r) {
      const int qg = q0 + hi * 4 + r;
      float v0 = s0[r] * SCALE; if ((k0 + lo) > qg || mv0 <= 0.f) v0 = -1e30f;
      float v1 = s1[r] * SCALE; if ((k0 + 16 + lo) > qg || mv1 <= 0.f) v1 = -1e30f;
      float tm = fmaxf(v0, v1);
      tm = fmaxf(tm, __shfl_xor(tm, 1));
      tm = fmaxf(tm, __shfl_xor(tm, 2));
      tm = fmaxf(tm, __shfl_xor(tm, 4));
      tm = fmaxf(tm, __shfl_xor(tm, 8));
      float mnew = fmaxf(mreg[r], tm);
      float corr = exp2f((mreg[r] - mnew) * LOG2E);
      float p0 = exp2f((v0 - mnew) * LOG2E);
      float p1 = exp2f((v1 - mnew) * LOG2E);
      float rs = p0 + p1;
      rs += __shfl_xor(rs, 1); rs += __shfl_xor(rs, 2);
      rs += __shfl_xor(rs, 4); rs += __shfl_xor(rs, 8);
      lreg[r] = lreg[r] * corr + rs;
      mreg[r] = mnew;
#pragma unroll
      for (int n = 0; n < 8; ++n) acc[n][r] *= corr;
      const int prow = hi * 4 + r;
      const int swz = (prow >> 1) & 3;
      const int c0 = lo, c1 = 16 + lo;
      Pw[prow * 32 + ((c0 >> 3) ^ swz) * 8 + (c0 & 7)] = f2bf(p0);
      Pw[prow * 32 + ((c1 >> 3) ^ swz) * 8 + (c1 & 7)] = f2bf(p1);
    }
    { // PV: one K=32 MFMA per 16-wide d block
      const int prow = lo;
      const int ss = hi ^ ((prow >> 1) & 3);
      s16x8 pa = *(const s16x8*)(Pw + prow * 32 + ss * 8);
#pragma unroll
      for (int n = 0; n < 8; ++n) {
        int vrow = n * 16 + lo;
        int vs = hi ^ ((vrow >> 1) & 3);
        s16x8 vf = *(const s16x8*)(Vs + vrow * 32 + vs * 8);
        acc[n] = __builtin_amdgcn_mfma_f32_16x16x32_bf16(pa, vf, acc[n], 0, 0, 0);
      }
    }
    __syncthreads();
  }
  float inv[4];
#pragma unroll
  for (int r = 0; r < 4; ++r) inv[r] = 1.0f / lreg[r];
#pragma unroll
  for (int n = 0; n < 8; ++n)
#pragma unroll
    for (int r = 0; r < 4; ++r) {
      int row = b * S_ + q0 + hi * 4 + r;
      int col = h * HD + n * 16 + lo;
      Ob[(size_t)row * D_ + col] = f2bf(acc[n][r] * inv[r]);
    }
}

// ---------------------------------------------------------------------------
// Orchestration. Workspace regions (bytes):
//  R1 [0,           50331648): Xb (33.5M) then {Qb 33.5M | Kb 8.4M | Vt 8.4M}
//  R2 [50331648,   100663296): WqkvT (50.3M) then {WoT 33.5M | Vb 8.4M}
//  R3 [100663296,  150994944): QKV bf16 (50.3M) then attn-out bf16 (33.5M)
// ---------------------------------------------------------------------------
extern "C" void kernel_launch(void* const* d_in, const int* in_sizes, int n_in,
                              void* d_out, int out_size, void* d_ws, size_t ws_size,
                              hipStream_t stream) {
  const float* X    = (const float*)d_in[0];
  const float* mask = (const float*)d_in[1];
  const int*   pos  = (const int*)d_in[2];
  const float* wq   = (const float*)d_in[3];
  const float* wk   = (const float*)d_in[4];
  const float* wv   = (const float*)d_in[5];
  const float* wo   = (const float*)d_in[6];
  float* out = (float*)d_out;
  char* ws = (char*)d_ws;

  const size_t R1 = 50331648, R2 = 50331648;
  u16* Xb  = (u16*)(ws);
  u16* Qb  = (u16*)(ws);                       // reuse (Xb dead after GEMM1)
  u16* Kb  = (u16*)(ws + 33554432);
  u16* Vt  = (u16*)(ws + 41943040);
  u16* WT  = (u16*)(ws + R1);
  u16* WoT = (u16*)(ws + R1);                  // reuse (WqkvT dead after GEMM1)
  u16* Vb  = (u16*)(ws + R1 + 33554432);
  u16* QKV = (u16*)(ws + R1 + R2);
  u16* Ab  = (u16*)(ws + R1 + R2);             // reuse (QKV dead after rope)

  cast_f32_bf16<<<dim3(16384), dim3(256), 0, stream>>>(X, Xb, M_ * D_ / 4);
  transpose_cast_w<<<dim3(128, 128), dim3(256), 0, stream>>>(wq, WT, 4096, 4096);
  transpose_cast_w<<<dim3(32, 128),  dim3(256), 0, stream>>>(wk, WT + (size_t)4096 * 4096, 4096, 1024);
  transpose_cast_w<<<dim3(32, 128),  dim3(256), 0, stream>>>(wv, WT + (size_t)5120 * 4096, 4096, 1024);
  gemm_bt<true><<<dim3(FQ / 128, M_ / 128), dim3(256), 0, stream>>>(Xb, WT, QKV, M_, FQ, D_);
  rope_split<<<dim3(M_), dim3(256), 0, stream>>>(QKV, pos, Qb, Kb, Vb);
  transpose_v16<<<dim3(4, 64, 16), dim3(256), 0, stream>>>(Vb, Vt);
  transpose_cast_w<<<dim3(128, 128), dim3(256), 0, stream>>>(wo, WoT, 4096, 4096);
  attn_fwd<<<dim3(S_ / 16, B_ * NKV), dim3(256), 0, stream>>>(Qb, Kb, Vt, mask, Ab);
  gemm_bt<false><<<dim3(D_ / 128, M_ / 128), dim3(256), 0, stream>>>(Ab, WoT, out, M_, D_, D_);
}

// Round 4
// 830.551 us; speedup vs baseline: 1.1752x; 1.1752x over previous
//
#include <hip/hip_runtime.h>
#include <hip/hip_bf16.h>

#define DEV __device__ __forceinline__

typedef unsigned short u16;
typedef unsigned int u32;
typedef unsigned long long u64;
typedef __attribute__((ext_vector_type(8))) short s16x8;   // 8 bf16 in 4 VGPRs
typedef __attribute__((ext_vector_type(4))) float f32x4;
typedef __attribute__((ext_vector_type(16))) float f32x16;
typedef __attribute__((ext_vector_type(4))) u32 u32x4;

constexpr int B_  = 2, S_ = 2048, D_ = 4096, NH = 32, NKV = 8, HD = 128;
constexpr int M_  = B_ * S_;        // 4096 rows of "tokens"
constexpr int FQ  = 6144;           // Q(4096) + K(1024) + V(1024)
constexpr float SCALE = 0.08838834764831845f;   // 1/sqrt(128)
constexpr float LOG2E = 1.4426950408889634f;
constexpr float C1F = SCALE * LOG2E;            // scale folded into exp2 domain
constexpr float LOG2_THETA = 18.931568569324174f; // log2(500000)

DEV u16 f2bf(float f) {
  u32 u = __builtin_bit_cast(u32, f);
  u32 r = u + 0x7fffu + ((u >> 16) & 1u);
  return (u16)(r >> 16);
}
DEV float bf2f(u16 h) { u32 u = ((u32)h) << 16; return __builtin_bit_cast(float, u); }

DEV void gload_lds16(const void* g, void* l) {
  __builtin_amdgcn_global_load_lds((const __attribute__((address_space(1))) u32*)g,
                                   (__attribute__((address_space(3))) u32*)l, 16, 0, 0);
}

DEV u32 cvtpk(float lo, float hi) {
  u32 r;
  asm("v_cvt_pk_bf16_f32 %0, %1, %2" : "=v"(r) : "v"(lo), "v"(hi));
  return r;
}

DEV void cfence() { asm volatile("" ::: "memory"); }

// ---------------------------------------------------------------------------
// elementwise f32 -> bf16 cast (vectorized)
// ---------------------------------------------------------------------------
struct alignas(8) U16x4 { u16 x, y, z, w; };

__global__ __launch_bounds__(256) void cast_f32_bf16(const float* __restrict__ src,
                                                     u16* __restrict__ dst, int n4) {
  int i = blockIdx.x * 256 + threadIdx.x;
  if (i < n4) {
    float4 v = ((const float4*)src)[i];
    U16x4 o; o.x = f2bf(v.x); o.y = f2bf(v.y); o.z = f2bf(v.z); o.w = f2bf(v.w);
    ((U16x4*)dst)[i] = o;
  }
}

// ---------------------------------------------------------------------------
// transpose + cast: src f32 [R][C] -> dst bf16 [C][R]
// ---------------------------------------------------------------------------
__global__ __launch_bounds__(256) void transpose_cast_w(const float* __restrict__ src,
                                                        u16* __restrict__ dst, int R, int C) {
  __shared__ float tile[32][33];
  const int tx = threadIdx.x & 31, ty = threadIdx.x >> 5;
  const int c0 = blockIdx.x * 32, r0 = blockIdx.y * 32;
#pragma unroll
  for (int i = 0; i < 4; ++i)
    tile[ty + i * 8][tx] = src[(size_t)(r0 + ty + i * 8) * C + c0 + tx];
  __syncthreads();
#pragma unroll
  for (int i = 0; i < 4; ++i)
    dst[(size_t)(c0 + ty + i * 8) * R + r0 + tx] = f2bf(tile[tx][ty + i * 8]);
}

// bf16 [S][HD] -> [HD][S] per head (16 heads in z)
__global__ __launch_bounds__(256) void transpose_v16(const u16* __restrict__ Vb,
                                                     u16* __restrict__ Vt) {
  __shared__ u16 tile[32][33];
  const int tx = threadIdx.x & 31, ty = threadIdx.x >> 5;
  const int d0 = blockIdx.x * 32, s0 = blockIdx.y * 32;
  const size_t head = blockIdx.z;
  const u16* sp = Vb + head * (size_t)S_ * HD;
  u16* dp = Vt + head * (size_t)HD * S_;
#pragma unroll
  for (int i = 0; i < 4; ++i)
    tile[ty + i * 8][tx] = sp[(size_t)(s0 + ty + i * 8) * HD + d0 + tx];
  __syncthreads();
#pragma unroll
  for (int i = 0; i < 4; ++i)
    dp[(size_t)(d0 + ty + i * 8) * S_ + s0 + tx] = tile[tx][ty + i * 8];
}

// ---------------------------------------------------------------------------
// GEMM: C[M][N] = A[M][K](bf16,row-major) * Bt[N][K](bf16,row-major, i.e. B^T)
// 128x128 tile, BK=32, 4 waves (2x2), double-buffered LDS via global_load_lds.
// ---------------------------------------------------------------------------
DEV void stage_tile(const u16* __restrict__ gtile, int ldg, u16* lds, int wid, int lane) {
#pragma unroll
  for (int i = 0; i < 2; ++i) {
    int c = (i * 4 + wid) * 64 + lane;       // chunk id 0..511
    int row = c >> 2, slot = c & 3;
    int ss = slot ^ ((row >> 1) & 3);
    gload_lds16(gtile + (size_t)row * ldg + ss * 8, lds + (size_t)(i * 4 + wid) * 512);
  }
}

DEV s16x8 frag64(const u16* lds, int row, int hi) {
  int ss = hi ^ ((row >> 1) & 3);
  return *(const s16x8*)(lds + row * 32 + ss * 8);
}

template <bool OUT_BF16>
__global__ __launch_bounds__(256) void gemm_bt(const u16* __restrict__ A,
                                               const u16* __restrict__ Bt,
                                               void* __restrict__ Cv,
                                               int Mm, int Nn, int Kk) {
  __shared__ u16 As[2][128 * 32];
  __shared__ u16 Bs[2][128 * 32];
  const int lane = threadIdx.x & 63, wid = threadIdx.x >> 6;
  const int lo = lane & 15, hi = lane >> 4;
  const int m0 = blockIdx.y * 128, n0 = blockIdx.x * 128;
  const u16* Ag = A + (size_t)m0 * Kk;
  const u16* Bg = Bt + (size_t)n0 * Kk;
  f32x4 acc[4][4] = {};
  const int nK = Kk >> 5;
  stage_tile(Ag, Kk, As[0], wid, lane);
  stage_tile(Bg, Kk, Bs[0], wid, lane);
  __syncthreads();
  const int wm = (wid >> 1) * 64, wn = (wid & 1) * 64;
  for (int kt = 0; kt < nK; ++kt) {
    const int cur = kt & 1;
    if (kt + 1 < nK) {
      stage_tile(Ag + (kt + 1) * 32, Kk, As[cur ^ 1], wid, lane);
      stage_tile(Bg + (kt + 1) * 32, Kk, Bs[cur ^ 1], wid, lane);
    }
    s16x8 af[4], bf[4];
#pragma unroll
    for (int t = 0; t < 4; ++t) af[t] = frag64(As[cur], wm + t * 16 + lo, hi);
#pragma unroll
    for (int t = 0; t < 4; ++t) bf[t] = frag64(Bs[cur], wn + t * 16 + lo, hi);
#pragma unroll
    for (int i = 0; i < 4; ++i)
#pragma unroll
      for (int j = 0; j < 4; ++j)
        acc[i][j] = __builtin_amdgcn_mfma_f32_16x16x32_bf16(af[i], bf[j], acc[i][j], 0, 0, 0);
    __syncthreads();
  }
#pragma unroll
  for (int i = 0; i < 4; ++i)
#pragma unroll
    for (int j = 0; j < 4; ++j)
#pragma unroll
      for (int r = 0; r < 4; ++r) {
        int row = m0 + wm + i * 16 + hi * 4 + r;
        int col = n0 + wn + j * 16 + lo;
        float v = acc[i][j][r];
        if (OUT_BF16) ((u16*)Cv)[(size_t)row * Nn + col] = f2bf(v);
        else          ((float*)Cv)[(size_t)row * Nn + col] = v;
      }
}

// ---------------------------------------------------------------------------
// RoPE + head split
// ---------------------------------------------------------------------------
__global__ __launch_bounds__(256) void rope_split(const u16* __restrict__ QKV,
                                                  const int* __restrict__ pos,
                                                  u16* __restrict__ Qb, u16* __restrict__ Kb,
                                                  u16* __restrict__ Vb) {
  const int row = blockIdx.x;              // b*S + s
  const int b = row >> 11, s = row & 2047;
  const float t = (float)pos[row];
  const u16* src = QKV + (size_t)row * FQ;
  for (int idx = threadIdx.x; idx < 2560; idx += 256) {
    int j; const u16* sp; u16* dp;
    if (idx < 2048) {
      int hh = idx >> 6; j = idx & 63;
      sp = src + hh * 128 + 2 * j;
      dp = Qb + ((size_t)(b * NH + hh) * S_ + s) * HD + 2 * j;
    } else {
      int p2 = idx - 2048; int kvh = p2 >> 6; j = p2 & 63;
      sp = src + 4096 + kvh * 128 + 2 * j;
      dp = Kb + ((size_t)(b * NKV + kvh) * S_ + s) * HD + 2 * j;
    }
    float a = bf2f(sp[0]), bb = bf2f(sp[1]);
    float ang = t * exp2f(-(float)j * (LOG2_THETA / 64.0f));
    float sn, cs; sincosf(ang, &sn, &cs);
    dp[0] = f2bf(a * cs - bb * sn);
    dp[1] = f2bf(a * sn + bb * cs);
  }
  for (int idx = threadIdx.x; idx < 1024; idx += 256) {
    int kvh = idx >> 7, hd = idx & 127;
    Vb[((size_t)(b * NKV + kvh) * S_ + s) * HD + hd] = src[5120 + idx];
  }
}

// ---------------------------------------------------------------------------
// Flash attention, m214-style: 4 waves = 4 GQA heads of one kv group; each
// wave owns QBLK=32 q-rows; KVBLK=64 double-buffered in LDS; swapped QK^T
// (mfma(K,Q)) -> per-lane P rows; in-register softmax (defer-max THR=8);
// P->bf16 via v_cvt_pk_bf16_f32 + shfl_xor(32) half-exchange; counted vmcnt(8).
// ---------------------------------------------------------------------------
template<int KB>
DEV void mask_tile(f32x16& st, int k0, int qg, int hs, bool padbad, float mvv) {
#pragma unroll
  for (int r = 0; r < 16; ++r) {
    int kl = KB * 32 + (r & 3) + 8 * (r >> 2) + 4 * hs;
    float s = st[r];
    if (k0 + kl > qg) s = -1e30f;
    if (padbad) { float mj = __shfl(mvv, kl); if (mj <= 0.f) s = -1e30f; }
    st[r] = s;
  }
}

DEV void stage_kv(const u16* __restrict__ Kg, const u16* __restrict__ Vg, int k0,
                  u16* KsB, u16* VsB, int wid, int lane) {
#pragma unroll
  for (int i = 0; i < 4; ++i) {              // K tile: 64 rows x 128 d, 16 slots/row
    int c = (i * 4 + wid) * 64 + lane;
    int row = c >> 4, sl = c & 15;
    gload_lds16(Kg + (size_t)(k0 + row) * HD + (sl ^ (row & 7)) * 8,
                KsB + (size_t)(i * 4 + wid) * 512);
  }
#pragma unroll
  for (int i = 0; i < 4; ++i) {              // V^T tile: 128 d-rows x 64 k, 8 slots/row
    int c = (i * 4 + wid) * 64 + lane;
    int row = c >> 3, sl = c & 7;
    gload_lds16(Vg + (size_t)row * S_ + k0 + (sl ^ (row & 7)) * 8,
                VsB + (size_t)(i * 4 + wid) * 512);
  }
}

DEV s16x8 kfrag(const u16* KsB, int kb, int dblk, int lane) {
  int row = kb * 32 + (lane & 31);
  int sl = (2 * dblk + (lane >> 5)) ^ (row & 7);
  return *(const s16x8*)(KsB + row * 128 + sl * 8);
}
DEV s16x8 vfrag(const u16* VsB, int ks, int dblk, int lane) {
  int row = dblk * 32 + (lane & 31);
  int sl = (2 * ks + (lane >> 5)) ^ (row & 7);
  return *(const s16x8*)(VsB + row * 64 + sl * 8);
}

__global__ __launch_bounds__(256, 2) void attn_fwd(const u16* __restrict__ Qb,
                                                   const u16* __restrict__ Kb,
                                                   const u16* __restrict__ Vt,
                                                   const float* __restrict__ mask,
                                                   u16* __restrict__ Ob) {
  __shared__ u16 Ks[2][64 * 128];
  __shared__ u16 Vs[2][128 * 64];
  const int lane = threadIdx.x & 63, wid = threadIdx.x >> 6;
  const int hs = lane >> 5;                    // lane half
  const int qt = (int)gridDim.x - 1 - (int)blockIdx.x;   // longest-first
  const int bkv = blockIdx.y;
  const int b = bkv >> 3, kv = bkv & 7;
  const int h = kv * 4 + wid;
  const int q0 = qt * 32;
  const int qg = q0 + (lane & 31);             // this lane's q row (softmax domain)
  const u16* Qg = Qb + ((size_t)(b * NH + h) * S_ + q0) * HD;
  const u16* Kg = Kb + (size_t)(b * NKV + kv) * S_ * HD;
  const u16* Vg = Vt + (size_t)(b * NKV + kv) * HD * S_;

  // Q fragments hoisted: lane holds Q[q0+(lane&31)][dblk*16 + 8*hs + e]
  s16x8 qf[8];
#pragma unroll
  for (int dblk = 0; dblk < 8; ++dblk)
    qf[dblk] = *(const s16x8*)(Qg + (size_t)(lane & 31) * HD + dblk * 16 + 8 * hs);

  f32x16 acc[4] = {};
  float m_run = -1e30f, mz = -1e30f, l_run = 0.f;
  const int nt = (q0 + 95) >> 6;

  stage_kv(Kg, Vg, 0, Ks[0], Vs[0], wid, lane);

  for (int t = 0; t < nt; ++t) {
    const int k0 = t * 64;
    const int cur = t & 1;
    float mvv = mask[b * S_ + k0 + lane];
    cfence();
    __builtin_amdgcn_s_barrier();            // buf[cur^1] free to overwrite
    if (t + 1 < nt) {
      stage_kv(Kg, Vg, k0 + 64, Ks[cur ^ 1], Vs[cur ^ 1], wid, lane);
      asm volatile("s_waitcnt vmcnt(8)" ::: "memory");
    } else {
      asm volatile("s_waitcnt vmcnt(0)" ::: "memory");
    }
    __builtin_amdgcn_s_barrier();            // buf[cur] staged for all waves
    cfence();

    const u16* KsB = Ks[cur];
    const u16* VsB = Vs[cur];

    // swapped QK^T: st[k-pattern][q = lane&31]
    f32x16 st0 = {}, st1 = {};
#pragma unroll
    for (int dblk = 0; dblk < 8; ++dblk) {
      s16x8 kf0 = kfrag(KsB, 0, dblk, lane);
      s16x8 kf1 = kfrag(KsB, 1, dblk, lane);
      st0 = __builtin_amdgcn_mfma_f32_32x32x16_bf16(kf0, qf[dblk], st0, 0, 0, 0);
      st1 = __builtin_amdgcn_mfma_f32_32x32x16_bf16(kf1, qf[dblk], st1, 0, 0, 0);
    }

    const bool padbad = (__ballot(mvv > 0.f) != ~0ull);
    if (t == nt - 1 || padbad) {
      mask_tile<0>(st0, k0, qg, hs, padbad, mvv);
      mask_tile<1>(st1, k0, qg, hs, padbad, mvv);
    }

    // in-lane tile max (raw S) + partner exchange
    float mx[16];
#pragma unroll
    for (int r = 0; r < 16; ++r) mx[r] = fmaxf(st0[r], st1[r]);
#pragma unroll
    for (int r = 0; r < 8; ++r) mx[r] = fmaxf(mx[r], mx[r + 8]);
#pragma unroll
    for (int r = 0; r < 4; ++r) mx[r] = fmaxf(mx[r], mx[r + 4]);
    float tm = fmaxf(fmaxf(mx[0], mx[1]), fmaxf(mx[2], mx[3]));
    float tmb = fmaxf(tm, __shfl_xor(tm, 32));

    // defer-max: rescale only when tile max exceeds running by >8 (log2 units)
    if (__any(tmb * C1F > mz + 8.f)) {
      float mzold = mz;
      m_run = fmaxf(m_run, tmb);
      mz = m_run * C1F;
      float corr = exp2f(mzold - mz);
      l_run *= corr;
#pragma unroll
      for (int r = 0; r < 16; ++r) {
        float cq = __shfl(corr, (r & 3) + 8 * (r >> 2) + 4 * hs);
        acc[0][r] *= cq; acc[1][r] *= cq; acc[2][r] *= cq; acc[3][r] *= cq;
      }
    }

    // exp (scale folded): p = 2^(s*C1 - mz)
    const float nmz = -mz;
#pragma unroll
    for (int r = 0; r < 16; ++r) {
      st0[r] = exp2f(fmaf(st0[r], C1F, nmz));
      st1[r] = exp2f(fmaf(st1[r], C1F, nmz));
    }

    // row sum (in-lane tree + partner)
    float sm[8];
#pragma unroll
    for (int i = 0; i < 8; ++i) sm[i] = (st0[i] + st0[i + 8]) + (st1[i] + st1[i + 8]);
#pragma unroll
    for (int i = 0; i < 4; ++i) sm[i] += sm[i + 4];
    float rs = (sm[0] + sm[1]) + (sm[2] + sm[3]);
    l_run += rs + __shfl_xor(rs, 32);

    // pack P -> bf16 A-fragments via cvt_pk + half-lane exchange (shfl_xor 32).
    // pa[ks] element e must be P[q=lane&31][16*ks + 8*hs + e].
    s16x8 pa[4];
#pragma unroll
    for (int ks = 0; ks < 4; ++ks) {
      const f32x16& src = (ks >= 2) ? st1 : st0;
      const int o = 8 * (ks & 1);
      u32 A0 = cvtpk(src[o + 0], src[o + 1]);   // k = 16ks + 4hs + {0,1}
      u32 A1 = cvtpk(src[o + 2], src[o + 3]);   // k = 16ks + 4hs + {2,3}
      u32 X0 = cvtpk(src[o + 4], src[o + 5]);   // k = 16ks + 8 + 4hs + {0,1}
      u32 X1 = cvtpk(src[o + 6], src[o + 7]);   // k = 16ks + 8 + 4hs + {2,3}
      u32 a0p = (u32)__shfl_xor((int)A0, 32);
      u32 a1p = (u32)__shfl_xor((int)A1, 32);
      u32 x0p = (u32)__shfl_xor((int)X0, 32);
      u32 x1p = (u32)__shfl_xor((int)X1, 32);
      u32x4 pw;
      pw[0] = hs ? x0p : A0;   // k = 16ks + 8hs + {0,1}
      pw[1] = hs ? x1p : A1;   // k = 16ks + 8hs + {2,3}
      pw[2] = hs ? X0 : a0p;   // k = 16ks + 8hs + {4,5}
      pw[3] = hs ? X1 : a1p;   // k = 16ks + 8hs + {6,7}
      pa[ks] = __builtin_bit_cast(s16x8, pw);
    }

    // PV: acc[dblk] += P * V
#pragma unroll
    for (int dblk = 0; dblk < 4; ++dblk)
#pragma unroll
      for (int ks = 0; ks < 4; ++ks) {
        s16x8 vf = vfrag(VsB, ks, dblk, lane);
        acc[dblk] = __builtin_amdgcn_mfma_f32_32x32x16_bf16(pa[ks], vf, acc[dblk], 0, 0, 0);
      }
  }

  // epilogue: divide by l (broadcast per-q via shfl), store bf16
  const float linv = 1.0f / l_run;
#pragma unroll
  for (int r = 0; r < 16; ++r) {
    const int qr = (r & 3) + 8 * (r >> 2) + 4 * hs;
    const float lv = __shfl(linv, qr);
    const size_t grow = (size_t)(b * S_ + q0 + qr);
#pragma unroll
    for (int dblk = 0; dblk < 4; ++dblk)
      Ob[grow * D_ + h * HD + dblk * 32 + (lane & 31)] = f2bf(acc[dblk][r] * lv);
  }
}

// ---------------------------------------------------------------------------
// Orchestration (workspace layout unchanged from round 0)
// ---------------------------------------------------------------------------
extern "C" void kernel_launch(void* const* d_in, const int* in_sizes, int n_in,
                              void* d_out, int out_size, void* d_ws, size_t ws_size,
                              hipStream_t stream) {
  const float* X    = (const float*)d_in[0];
  const float* mask = (const float*)d_in[1];
  const int*   pos  = (const int*)d_in[2];
  const float* wq   = (const float*)d_in[3];
  const float* wk   = (const float*)d_in[4];
  const float* wv   = (const float*)d_in[5];
  const float* wo   = (const float*)d_in[6];
  float* out = (float*)d_out;
  char* ws = (char*)d_ws;

  const size_t R1 = 50331648, R2 = 50331648;
  u16* Xb  = (u16*)(ws);
  u16* Qb  = (u16*)(ws);                       // reuse (Xb dead after GEMM1)
  u16* Kb  = (u16*)(ws + 33554432);
  u16* Vt  = (u16*)(ws + 41943040);
  u16* WT  = (u16*)(ws + R1);
  u16* WoT = (u16*)(ws + R1);                  // reuse (WqkvT dead after GEMM1)
  u16* Vb  = (u16*)(ws + R1 + 33554432);
  u16* QKV = (u16*)(ws + R1 + R2);
  u16* Ab  = (u16*)(ws + R1 + R2);             // reuse (QKV dead after rope)

  cast_f32_bf16<<<dim3(16384), dim3(256), 0, stream>>>(X, Xb, M_ * D_ / 4);
  transpose_cast_w<<<dim3(128, 128), dim3(256), 0, stream>>>(wq, WT, 4096, 4096);
  transpose_cast_w<<<dim3(32, 128),  dim3(256), 0, stream>>>(wk, WT + (size_t)4096 * 4096, 4096, 1024);
  transpose_cast_w<<<dim3(32, 128),  dim3(256), 0, stream>>>(wv, WT + (size_t)5120 * 4096, 4096, 1024);
  gemm_bt<true><<<dim3(FQ / 128, M_ / 128), dim3(256), 0, stream>>>(Xb, WT, QKV, M_, FQ, D_);
  rope_split<<<dim3(M_), dim3(256), 0, stream>>>(QKV, pos, Qb, Kb, Vb);
  transpose_v16<<<dim3(4, 64, 16), dim3(256), 0, stream>>>(Vb, Vt);
  transpose_cast_w<<<dim3(128, 128), dim3(256), 0, stream>>>(wo, WoT, 4096, 4096);
  attn_fwd<<<dim3(S_ / 32, B_ * NKV), dim3(256), 0, stream>>>(Qb, Kb, Vt, mask, Ab);
  gemm_bt<false><<<dim3(D_ / 128, M_ / 128), dim3(256), 0, stream>>>(Ab, WoT, out, M_, D_, D_);
}